// Round 5
// baseline (1116.437 us; speedup 1.0000x reference)
//
#include <hip/hip_runtime.h>
#include <math.h>

#define NCLASSES   10000
#define NCLASSES4  2500            // NCLASSES / 4
#define NT         256             // threads per block (4 waves)
#define NITER      10              // ceil(2500/256)
#define IGNORE_INDEX (-1)

#define SMOOTH_UNIF  1e-5          // SMOOTHING / CLASSES
#define SMOOTH_COMPL 0.9           // 1 - SMOOTHING

// Single-pass focal CE via moment decomposition:
//   (1-p)^3 * ls = (1 - 3p + 3p^2 - p^3) * ls,  p = e^x / Z, ls = x - lse
//   => sum_j w_j is a linear combination of
//      S0=Σx, Z1=Σe^x, A1=Σe^x·x, Z2=Σe^2x, A2=Σe^2x·x, Z3=Σe^3x, A3=Σe^3x·x
// One streaming pass, 7 scalar accumulators, no row residency in registers.
// Final scalar mean fused via device-scope atomics + last-block ticket.
__global__ __launch_bounds__(NT)
void focal_ce_moments(const float* __restrict__ logits,
                      const int* __restrict__ target,
                      float* __restrict__ acc,        // [0]=loss sum, [1]=mask sum
                      unsigned* __restrict__ ticket,  // [0]=blocks done
                      float* __restrict__ out,
                      int n_rows) {
    const int row = blockIdx.x;
    const int t = threadIdx.x;
    const float* __restrict__ xrow = logits + (size_t)row * NCLASSES;
    const float4* __restrict__ xrow4 = reinterpret_cast<const float4*>(xrow);
    const int tgt = target[row];

    // thread 0 fetches the target logit directly (one 4B load, latency hidden
    // under the streaming loop)
    float xt = 0.0f;
    if (t == 0 && tgt >= 0) xt = xrow[tgt];

    float s0 = 0.f, z1 = 0.f, a1 = 0.f, z2 = 0.f, a2 = 0.f, z3 = 0.f, a3 = 0.f;

    #pragma unroll
    for (int i = 0; i < NITER; i++) {
        int idx4 = t + i * NT;
        if (idx4 < NCLASSES4) {             // only i==9 can fail
            float4 x = xrow4[idx4];
            {
                float e = __expf(x.x), e2 = e * e, e3 = e2 * e;
                s0 += x.x; z1 += e; z2 += e2; z3 += e3;
                a1 = fmaf(e, x.x, a1); a2 = fmaf(e2, x.x, a2); a3 = fmaf(e3, x.x, a3);
            }
            {
                float e = __expf(x.y), e2 = e * e, e3 = e2 * e;
                s0 += x.y; z1 += e; z2 += e2; z3 += e3;
                a1 = fmaf(e, x.y, a1); a2 = fmaf(e2, x.y, a2); a3 = fmaf(e3, x.y, a3);
            }
            {
                float e = __expf(x.z), e2 = e * e, e3 = e2 * e;
                s0 += x.z; z1 += e; z2 += e2; z3 += e3;
                a1 = fmaf(e, x.z, a1); a2 = fmaf(e2, x.z, a2); a3 = fmaf(e3, x.z, a3);
            }
            {
                float e = __expf(x.w), e2 = e * e, e3 = e2 * e;
                s0 += x.w; z1 += e; z2 += e2; z3 += e3;
                a1 = fmaf(e, x.w, a1); a2 = fmaf(e2, x.w, a2); a3 = fmaf(e3, x.w, a3);
            }
        }
    }

    // ---- wave-level reduce of the 7 moments ----
    #pragma unroll
    for (int off = 32; off > 0; off >>= 1) {
        s0 += __shfl_down(s0, off, 64);
        z1 += __shfl_down(z1, off, 64);
        a1 += __shfl_down(a1, off, 64);
        z2 += __shfl_down(z2, off, 64);
        a2 += __shfl_down(a2, off, 64);
        z3 += __shfl_down(z3, off, 64);
        a3 += __shfl_down(a3, off, 64);
    }

    __shared__ float red[7][NT / 64];
    const int w = t >> 6;
    if ((t & 63) == 0) {
        red[0][w] = s0; red[1][w] = z1; red[2][w] = a1;
        red[3][w] = z2; red[4][w] = a2; red[5][w] = z3; red[6][w] = a3;
    }
    __syncthreads();

    if (t == 0) {
        double S0 = 0, Z1 = 0, A1 = 0, Z2 = 0, A2 = 0, Z3 = 0, A3 = 0;
        #pragma unroll
        for (int j = 0; j < NT / 64; j++) {
            S0 += red[0][j]; Z1 += red[1][j]; A1 += red[2][j];
            Z2 += red[3][j]; A2 += red[4][j]; Z3 += red[5][j]; A3 += red[6][j];
        }
        float loss = 0.0f, msk = 0.0f;
        if (tgt != IGNORE_INDEX) {
            double lse = log(Z1);
            double SL = S0 - (double)NCLASSES * lse;         // Σ ls
            double T1 = (A1 - lse * Z1) / Z1;                // Σ p·ls
            double T2 = (A2 - lse * Z2) / (Z1 * Z1);         // Σ p²·ls
            double T3 = (A3 - lse * Z3) / (Z1 * Z1 * Z1);    // Σ p³·ls
            double W = SL - 3.0 * T1 + 3.0 * T2 - T3;
            double ls_t = (double)xt - lse;
            double pt = exp(ls_t);
            double om = 1.0 - pt;
            double w_t = om * om * om * ls_t;
            loss = (float)(-(SMOOTH_UNIF * W + SMOOTH_COMPL * w_t));
            msk = 1.0f;
        }
        atomicAdd(&acc[0], loss);   // device-scope by default on gfx950
        atomicAdd(&acc[1], msk);
        __threadfence();            // release our adds before the ticket
        unsigned prev = __hip_atomic_fetch_add(ticket, 1u,
                                               __ATOMIC_ACQ_REL,
                                               __HIP_MEMORY_SCOPE_AGENT);
        if (prev == (unsigned)(n_rows - 1)) {
            float S = __hip_atomic_load(&acc[0], __ATOMIC_RELAXED,
                                        __HIP_MEMORY_SCOPE_AGENT);
            float C = __hip_atomic_load(&acc[1], __ATOMIC_RELAXED,
                                        __HIP_MEMORY_SCOPE_AGENT);
            out[0] = S / C;
        }
    }
}

extern "C" void kernel_launch(void* const* d_in, const int* in_sizes, int n_in,
                              void* d_out, int out_size, void* d_ws, size_t ws_size,
                              hipStream_t stream) {
    const float* logits = (const float*)d_in[0];
    const int* target = (const int*)d_in[1];
    const int n_tok = in_sizes[1];          // B*S = 8192

    float* acc = (float*)d_ws;              // acc[0]=loss sum, acc[1]=mask sum
    unsigned* ticket = (unsigned*)d_ws + 2; // ticket[0]

    // zero the accumulator state (ws is poisoned 0xAA pre-launch)
    hipMemsetAsync(d_ws, 0, 16, stream);

    focal_ce_moments<<<n_tok, NT, 0, stream>>>(logits, target, acc, ticket,
                                               (float*)d_out, n_tok);
}